// Round 4
// baseline (424.959 us; speedup 1.0000x reference)
//
#include <hip/hip_runtime.h>

#define BS 64
#define TT 2048
#define NJ 24
#define ROWF 99            // 24*4 quats + 3 pos
#define BLOCK 256
#define RPB 128            // rows per block: 2 row-groups of 64, x2 part-waves
#define NROWS (BS * TT)    // 131072 rows

// 16B load at 4B alignment (rows are 396B-strided): gfx950 handles dword-aligned
// dwordx4 in HW (may split lines).
__device__ __forceinline__ void ld4u(const float* __restrict__ p, float* q) {
  const float4 v = *reinterpret_cast<const float4*>(p);
  q[0] = v.x; q[1] = v.y; q[2] = v.z; q[3] = v.w;
}

__device__ __forceinline__ void quat2mat_s(const float* q, float s, float* R) {
  const float w = q[0], x = q[1], y = q[2], z = q[3];
  const float xx = s*x*x, yy = s*y*y, zz = s*z*z;
  const float xy = s*x*y, xz = s*x*z, yz = s*y*z;
  const float xw = s*x*w, yw = s*y*w, zw = s*z*w;
  R[0] = 1.0f - (yy+zz); R[1] = xy - zw;        R[2] = xz + yw;
  R[3] = xy + zw;        R[4] = 1.0f - (xx+zz); R[5] = yz - xw;
  R[6] = xz - yw;        R[7] = yz + xw;        R[8] = 1.0f - (xx+yy);
}

__device__ __forceinline__ void mm3(const float* A, const float* B, float* C) {
#pragma unroll
  for (int r = 0; r < 3; ++r) {
#pragma unroll
    for (int c = 0; c < 3; ++c) {
      C[3*r+c] = fmaf(A[3*r], B[c], fmaf(A[3*r+1], B[3+c], A[3*r+2]*B[6+c]));
    }
  }
}

// TREE-SPLIT decomposition (round-3 lesson: keep X+Y interleaved per thread for
// ILP; add waves with NO per-step communication). TOPOLOGY splits after spine
// 0->3->6->9 into two 10-joint halves. Each part recomputes the 4-joint spine:
//   PART 0: 0 + {1,4,7,10} + {2,5,8,11} + 3,6,9 + {12,15}     (14 joints, owns 14 diffs + pos)
//   PART 1: 0,3,6,9 + {13,16,18,20,22} + {14,17,19,21,23}     (14 joints, owns 10 diffs)
// Each thread runs BOTH X and Y chains (interleaved, 2-way ILP), carrying
// D = gtrY - gtrX. Squared-diff terms each have exactly one owner -> no shuffles.
// Waves alternate parts: branch is wave-uniform -> no divergence.
template<int PART>
__device__ __forceinline__ void fk_part(const float* __restrict__ xr,
                                        const float* __restrict__ yr,
                                        const float* __restrict__ tX,
                                        const float* __restrict__ tY,
                                        float& rot_acc, float& gtr_acc, float& pos_acc) {
  float GX[2][9], GY[2][9], D[2][3];

  // ---- joint 0 (root): both parts compute, only PART 0 accumulates ----
  {
    float xq[4], yq[4];
    ld4u(xr, xq); ld4u(yr, yq);
    const float qqx = xq[0]*xq[0] + xq[1]*xq[1] + xq[2]*xq[2] + xq[3]*xq[3];
    const float qqy = yq[0]*yq[0] + yq[1]*yq[1] + yq[2]*yq[2] + yq[3]*yq[3];
    if (PART == 0) {
      const float ix = 1.0f / fmaxf(sqrtf(qqx), 1e-12f);
      const float iy = 1.0f / fmaxf(sqrtf(qqy), 1e-12f);
      const float r0 = yq[0]*iy - xq[0]*ix, r1 = yq[1]*iy - xq[1]*ix;
      const float r2 = yq[2]*iy - xq[2]*ix, r3 = yq[3]*iy - xq[3]*ix;
      rot_acc += r0*r0 + r1*r1 + r2*r2 + r3*r3;
    }
    quat2mat_s(xq, 2.0f / qqx, GX[0]);
    quat2mat_s(yq, 2.0f / qqy, GY[0]);
    float xp[4], yp[4];
    ld4u(xr + 95, xp); ld4u(yr + 95, yp);   // floats [95..98]; pos = [96..98]
    D[0][0] = yp[1] - xp[1]; D[0][1] = yp[2] - xp[2]; D[0][2] = yp[3] - xp[3];
    if (PART == 0) {
      const float dd = D[0][0]*D[0][0] + D[0][1]*D[0][1] + D[0][2]*D[0][2];
      gtr_acc += dd;      // root contributes to gtr MSE
      pos_acc  = dd;      // and to the pos MSE
    }
  }

#define JSTEP(j, PS, NS, ACC) do {                                             \
    float xq[4], yq[4];                                                        \
    ld4u(xr + 4*(j), xq); ld4u(yr + 4*(j), yq);                                \
    const float qqx = xq[0]*xq[0] + xq[1]*xq[1] + xq[2]*xq[2] + xq[3]*xq[3];   \
    const float qqy = yq[0]*yq[0] + yq[1]*yq[1] + yq[2]*yq[2] + yq[3]*yq[3];   \
    if (ACC) {                                                                 \
      const float ix = 1.0f / fmaxf(sqrtf(qqx), 1e-12f);                       \
      const float iy = 1.0f / fmaxf(sqrtf(qqy), 1e-12f);                       \
      const float r0 = yq[0]*iy - xq[0]*ix, r1 = yq[1]*iy - xq[1]*ix;          \
      const float r2 = yq[2]*iy - xq[2]*ix, r3 = yq[3]*iy - xq[3]*ix;          \
      rot_acc += r0*r0 + r1*r1 + r2*r2 + r3*r3;                                \
    }                                                                          \
    const float tx0 = tX[3*(j)], tx1 = tX[3*(j)+1], tx2 = tX[3*(j)+2];         \
    const float ty0 = tY[3*(j)], ty1 = tY[3*(j)+1], ty2 = tY[3*(j)+2];         \
    const float vx0 = fmaf(GX[PS][0],tx0, fmaf(GX[PS][1],tx1, GX[PS][2]*tx2)); \
    const float vx1 = fmaf(GX[PS][3],tx0, fmaf(GX[PS][4],tx1, GX[PS][5]*tx2)); \
    const float vx2 = fmaf(GX[PS][6],tx0, fmaf(GX[PS][7],tx1, GX[PS][8]*tx2)); \
    const float vy0 = fmaf(GY[PS][0],ty0, fmaf(GY[PS][1],ty1, GY[PS][2]*ty2)); \
    const float vy1 = fmaf(GY[PS][3],ty0, fmaf(GY[PS][4],ty1, GY[PS][5]*ty2)); \
    const float vy2 = fmaf(GY[PS][6],ty0, fmaf(GY[PS][7],ty1, GY[PS][8]*ty2)); \
    const float d0 = D[PS][0] + (vy0 - vx0);                                   \
    const float d1 = D[PS][1] + (vy1 - vx1);                                   \
    const float d2 = D[PS][2] + (vy2 - vx2);                                   \
    if (ACC) gtr_acc += d0*d0 + d1*d1 + d2*d2;                                 \
    float RX[9], RY[9], GnX[9], GnY[9];                                        \
    quat2mat_s(xq, 2.0f / qqx, RX);                                            \
    quat2mat_s(yq, 2.0f / qqy, RY);                                            \
    mm3(GX[PS], RX, GnX);                                                      \
    mm3(GY[PS], RY, GnY);                                                      \
    _Pragma("unroll")                                                          \
    for (int k = 0; k < 9; ++k) { GX[NS][k] = GnX[k]; GY[NS][k] = GnY[k]; }    \
    D[NS][0] = d0; D[NS][1] = d1; D[NS][2] = d2;                               \
  } while (0)

  if (PART == 0) {
    JSTEP( 1, 0, 1, 1); JSTEP( 4, 1, 1, 1); JSTEP( 7, 1, 1, 1); JSTEP(10, 1, 1, 1);
    JSTEP( 2, 0, 1, 1); JSTEP( 5, 1, 1, 1); JSTEP( 8, 1, 1, 1); JSTEP(11, 1, 1, 1);
    JSTEP( 3, 0, 0, 1); JSTEP( 6, 0, 0, 1); JSTEP( 9, 0, 0, 1);
    JSTEP(12, 0, 0, 1); JSTEP(15, 0, 0, 1);
  } else {
    JSTEP( 3, 0, 0, 0); JSTEP( 6, 0, 0, 0); JSTEP( 9, 0, 0, 0);   // spine, no acc
    JSTEP(13, 0, 1, 1); JSTEP(16, 1, 1, 1); JSTEP(18, 1, 1, 1); JSTEP(20, 1, 1, 1); JSTEP(22, 1, 1, 1);
    JSTEP(14, 0, 1, 1); JSTEP(17, 1, 1, 1); JSTEP(19, 1, 1, 1); JSTEP(21, 1, 1, 1); JSTEP(23, 1, 1, 1);
  }
#undef JSTEP
}

__global__ __launch_bounds__(BLOCK, 4) void motion_loss_kernel(
    const float* __restrict__ Ym, const float* __restrict__ Xm,
    const float* __restrict__ Yt, const float* __restrict__ Xt,
    float* __restrict__ out) {
  __shared__ float ts[2][NJ * 3];   // 576 B: t-vectors for this block's batch

  const int tid = threadIdx.x;
  const int wv = tid >> 6;                              // wave 0..3
  const int part = wv & 1;                              // waves alternate tree-halves
  const size_t row = (size_t)blockIdx.x * RPB + (size_t)(wv >> 1) * 64 + (tid & 63);
  const int b = (int)(((size_t)blockIdx.x * RPB) / TT); // block stays in one batch

  if (tid < NJ * 3)                        ts[0][tid]       = Xt[(size_t)b * NJ * 3 + tid];
  else if (tid >= 128 && tid < 128 + NJ*3) ts[1][tid - 128] = Yt[(size_t)b * NJ * 3 + (tid - 128)];
  __syncthreads();

  const float* __restrict__ xr = Xm + row * ROWF;
  const float* __restrict__ yr = Ym + row * ROWF;

  float rot_acc = 0.0f, gtr_acc = 0.0f, pos_acc = 0.0f;
  if (part == 0) fk_part<0>(xr, yr, ts[0], ts[1], rot_acc, gtr_acc, pos_acc);
  else           fk_part<1>(xr, yr, ts[0], ts[1], rot_acc, gtr_acc, pos_acc);

  const float c_rot = 1.0f / ((float)NROWS * NJ * 4);   // B1 * mean over (bs,T,24,4)
  const float c_gtr = 2.5f / ((float)NROWS * NJ * 3);   // B2 * 2.5 * mean over (bs,T,24,3)
  const float c_pos = 1.0f / ((float)NROWS * 3);        // B2 * mean over (bs,T,3)
  float contrib = c_rot * rot_acc + c_gtr * gtr_acc + c_pos * pos_acc;
#pragma unroll
  for (int o = 32; o > 0; o >>= 1) contrib += __shfl_down(contrib, o, 64);
  if ((tid & 63) == 0) atomicAdd(out, contrib);
}

extern "C" void kernel_launch(void* const* d_in, const int* in_sizes, int n_in,
                              void* d_out, int out_size, void* d_ws, size_t ws_size,
                              hipStream_t stream) {
  const float* Ym = (const float*)d_in[0];
  const float* Xm = (const float*)d_in[1];
  const float* Yt = (const float*)d_in[2];
  const float* Xt = (const float*)d_in[3];
  float* out = (float*)d_out;
  hipMemsetAsync(out, 0, sizeof(float), stream);  // graph-capturable
  motion_loss_kernel<<<NROWS / RPB, BLOCK, 0, stream>>>(Ym, Xm, Yt, Xt, out);
}

// Round 6
// 233.022 us; speedup vs baseline: 1.8237x; 1.8237x over previous
//
#include <hip/hip_runtime.h>

#define BS 64
#define TT 2048
#define NJ 24
#define ROWF 99            // 24*4 quats + 3 pos
#define BLOCK 128          // 2 waves: wave0 -> PART 0, wave1 -> PART 1, same 64 rows
#define RPB 64             // rows per block
#define NROWS (BS * TT)    // 131072 rows

// 16B load at 4B alignment (rows are 396B-strided): gfx950 handles dword-aligned
// dwordx4 in HW (may split lines).
__device__ __forceinline__ void ld4u(const float* __restrict__ p, float* q) {
  const float4 v = *reinterpret_cast<const float4*>(p);
  q[0] = v.x; q[1] = v.y; q[2] = v.z; q[3] = v.w;
}

__device__ __forceinline__ void quat2mat_s(const float* q, float s, float* R) {
  const float w = q[0], x = q[1], y = q[2], z = q[3];
  const float xx = s*x*x, yy = s*y*y, zz = s*z*z;
  const float xy = s*x*y, xz = s*x*z, yz = s*y*z;
  const float xw = s*x*w, yw = s*y*w, zw = s*z*w;
  R[0] = 1.0f - (yy+zz); R[1] = xy - zw;        R[2] = xz + yw;
  R[3] = xy + zw;        R[4] = 1.0f - (xx+zz); R[5] = yz - xw;
  R[6] = xz - yw;        R[7] = yz + xw;        R[8] = 1.0f - (xx+yy);
}

__device__ __forceinline__ void mm3(const float* A, const float* B, float* C) {
#pragma unroll
  for (int r = 0; r < 3; ++r) {
#pragma unroll
    for (int c = 0; c < 3; ++c) {
      C[3*r+c] = fmaf(A[3*r], B[c], fmaf(A[3*r+1], B[3+c], A[3*r+2]*B[6+c]));
    }
  }
}

// TREE-SPLIT decomposition. TOPOLOGY splits after spine 0->3->6->9:
//   PART 0: 0 + {1,4,7,10} + {2,5,8,11} + 3,6,9 + {12,15}   (accumulates 14 joints + pos)
//   PART 1: 0,3,6,9 (no acc) + {13,16,18,20,22} + {14,17,19,21,23}  (accumulates 10)
// Each thread runs BOTH X and Y chains interleaved (2-way ILP), carrying
// D = gtrY - gtrX. Every squared-diff term has exactly one owner -> no shuffles.
// Parts are assigned per-WAVE -> branch is wave-uniform, no divergence.
// ROUND-4 LESSON: launch_bounds(256,4) VGPR-capped this ~110-float live set ->
// full scratch demotion (515 MB scratch writes). Bound must leave cap >= ~128.
template<int PART>
__device__ __forceinline__ void fk_part(const float* __restrict__ xr,
                                        const float* __restrict__ yr,
                                        const float* __restrict__ tX,
                                        const float* __restrict__ tY,
                                        float& rot_acc, float& gtr_acc, float& pos_acc) {
  float GX[2][9], GY[2][9], D[2][3];

  // ---- joint 0 (root): both parts compute, only PART 0 accumulates ----
  {
    float xq[4], yq[4];
    ld4u(xr, xq); ld4u(yr, yq);
    const float qqx = xq[0]*xq[0] + xq[1]*xq[1] + xq[2]*xq[2] + xq[3]*xq[3];
    const float qqy = yq[0]*yq[0] + yq[1]*yq[1] + yq[2]*yq[2] + yq[3]*yq[3];
    if (PART == 0) {
      const float ix = 1.0f / fmaxf(sqrtf(qqx), 1e-12f);
      const float iy = 1.0f / fmaxf(sqrtf(qqy), 1e-12f);
      const float r0 = yq[0]*iy - xq[0]*ix, r1 = yq[1]*iy - xq[1]*ix;
      const float r2 = yq[2]*iy - xq[2]*ix, r3 = yq[3]*iy - xq[3]*ix;
      rot_acc += r0*r0 + r1*r1 + r2*r2 + r3*r3;
    }
    quat2mat_s(xq, 2.0f / qqx, GX[0]);
    quat2mat_s(yq, 2.0f / qqy, GY[0]);
    float xp[4], yp[4];
    ld4u(xr + 95, xp); ld4u(yr + 95, yp);   // floats [95..98]; pos = [96..98]
    D[0][0] = yp[1] - xp[1]; D[0][1] = yp[2] - xp[2]; D[0][2] = yp[3] - xp[3];
    if (PART == 0) {
      const float dd = D[0][0]*D[0][0] + D[0][1]*D[0][1] + D[0][2]*D[0][2];
      gtr_acc += dd;      // root contributes to gtr MSE
      pos_acc  = dd;      // and to the pos MSE
    }
  }

#define JSTEP(j, PS, NS, ACC) do {                                             \
    float xq[4], yq[4];                                                        \
    ld4u(xr + 4*(j), xq); ld4u(yr + 4*(j), yq);                                \
    const float qqx = xq[0]*xq[0] + xq[1]*xq[1] + xq[2]*xq[2] + xq[3]*xq[3];   \
    const float qqy = yq[0]*yq[0] + yq[1]*yq[1] + yq[2]*yq[2] + yq[3]*yq[3];   \
    if (ACC) {                                                                 \
      const float ix = 1.0f / fmaxf(sqrtf(qqx), 1e-12f);                       \
      const float iy = 1.0f / fmaxf(sqrtf(qqy), 1e-12f);                       \
      const float r0 = yq[0]*iy - xq[0]*ix, r1 = yq[1]*iy - xq[1]*ix;          \
      const float r2 = yq[2]*iy - xq[2]*ix, r3 = yq[3]*iy - xq[3]*ix;          \
      rot_acc += r0*r0 + r1*r1 + r2*r2 + r3*r3;                                \
    }                                                                          \
    const float tx0 = tX[3*(j)], tx1 = tX[3*(j)+1], tx2 = tX[3*(j)+2];         \
    const float ty0 = tY[3*(j)], ty1 = tY[3*(j)+1], ty2 = tY[3*(j)+2];         \
    const float vx0 = fmaf(GX[PS][0],tx0, fmaf(GX[PS][1],tx1, GX[PS][2]*tx2)); \
    const float vx1 = fmaf(GX[PS][3],tx0, fmaf(GX[PS][4],tx1, GX[PS][5]*tx2)); \
    const float vx2 = fmaf(GX[PS][6],tx0, fmaf(GX[PS][7],tx1, GX[PS][8]*tx2)); \
    const float vy0 = fmaf(GY[PS][0],ty0, fmaf(GY[PS][1],ty1, GY[PS][2]*ty2)); \
    const float vy1 = fmaf(GY[PS][3],ty0, fmaf(GY[PS][4],ty1, GY[PS][5]*ty2)); \
    const float vy2 = fmaf(GY[PS][6],ty0, fmaf(GY[PS][7],ty1, GY[PS][8]*ty2)); \
    const float d0 = D[PS][0] + (vy0 - vx0);                                   \
    const float d1 = D[PS][1] + (vy1 - vx1);                                   \
    const float d2 = D[PS][2] + (vy2 - vx2);                                   \
    if (ACC) gtr_acc += d0*d0 + d1*d1 + d2*d2;                                 \
    float RX[9], RY[9], GnX[9], GnY[9];                                        \
    quat2mat_s(xq, 2.0f / qqx, RX);                                            \
    quat2mat_s(yq, 2.0f / qqy, RY);                                            \
    mm3(GX[PS], RX, GnX);                                                      \
    mm3(GY[PS], RY, GnY);                                                      \
    _Pragma("unroll")                                                          \
    for (int k = 0; k < 9; ++k) { GX[NS][k] = GnX[k]; GY[NS][k] = GnY[k]; }    \
    D[NS][0] = d0; D[NS][1] = d1; D[NS][2] = d2;                               \
  } while (0)

  if (PART == 0) {
    JSTEP( 1, 0, 1, 1); JSTEP( 4, 1, 1, 1); JSTEP( 7, 1, 1, 1); JSTEP(10, 1, 1, 1);
    JSTEP( 2, 0, 1, 1); JSTEP( 5, 1, 1, 1); JSTEP( 8, 1, 1, 1); JSTEP(11, 1, 1, 1);
    JSTEP( 3, 0, 0, 1); JSTEP( 6, 0, 0, 1); JSTEP( 9, 0, 0, 1);
    JSTEP(12, 0, 0, 1); JSTEP(15, 0, 0, 1);
  } else {
    JSTEP( 3, 0, 0, 0); JSTEP( 6, 0, 0, 0); JSTEP( 9, 0, 0, 0);   // spine, no acc
    JSTEP(13, 0, 1, 1); JSTEP(16, 1, 1, 1); JSTEP(18, 1, 1, 1); JSTEP(20, 1, 1, 1); JSTEP(22, 1, 1, 1);
    JSTEP(14, 0, 1, 1); JSTEP(17, 1, 1, 1); JSTEP(19, 1, 1, 1); JSTEP(21, 1, 1, 1); JSTEP(23, 1, 1, 1);
  }
#undef JSTEP
}

__global__ __launch_bounds__(BLOCK, 2) void motion_loss_kernel(
    const float* __restrict__ Ym, const float* __restrict__ Xm,
    const float* __restrict__ Yt, const float* __restrict__ Xt,
    float* __restrict__ out) {
  __shared__ float ts[2][NJ * 3];   // 576 B: t-vectors for this block's batch

  const int tid = threadIdx.x;
  const int part = tid >> 6;                             // wave 0 -> part 0, wave 1 -> part 1
  const size_t row = (size_t)blockIdx.x * RPB + (tid & 63);
  const int b = (int)(((size_t)blockIdx.x * RPB) / TT);  // block stays in one batch

  for (int i = tid; i < 2 * NJ * 3; i += BLOCK) {
    if (i < NJ * 3) ts[0][i]          = Xt[(size_t)b * NJ * 3 + i];
    else            ts[1][i - NJ * 3] = Yt[(size_t)b * NJ * 3 + (i - NJ * 3)];
  }
  __syncthreads();

  const float* __restrict__ xr = Xm + row * ROWF;
  const float* __restrict__ yr = Ym + row * ROWF;

  float rot_acc = 0.0f, gtr_acc = 0.0f, pos_acc = 0.0f;
  if (part == 0) fk_part<0>(xr, yr, ts[0], ts[1], rot_acc, gtr_acc, pos_acc);
  else           fk_part<1>(xr, yr, ts[0], ts[1], rot_acc, gtr_acc, pos_acc);

  const float c_rot = 1.0f / ((float)NROWS * NJ * 4);   // B1 * mean over (bs,T,24,4)
  const float c_gtr = 2.5f / ((float)NROWS * NJ * 3);   // B2 * 2.5 * mean over (bs,T,24,3)
  const float c_pos = 1.0f / ((float)NROWS * 3);        // B2 * mean over (bs,T,3)
  float contrib = c_rot * rot_acc + c_gtr * gtr_acc + c_pos * pos_acc;
#pragma unroll
  for (int o = 32; o > 0; o >>= 1) contrib += __shfl_down(contrib, o, 64);
  if ((tid & 63) == 0) atomicAdd(out, contrib);
}

extern "C" void kernel_launch(void* const* d_in, const int* in_sizes, int n_in,
                              void* d_out, int out_size, void* d_ws, size_t ws_size,
                              hipStream_t stream) {
  const float* Ym = (const float*)d_in[0];
  const float* Xm = (const float*)d_in[1];
  const float* Yt = (const float*)d_in[2];
  const float* Xt = (const float*)d_in[3];
  float* out = (float*)d_out;
  hipMemsetAsync(out, 0, sizeof(float), stream);  // graph-capturable
  motion_loss_kernel<<<NROWS / RPB, BLOCK, 0, stream>>>(Ym, Xm, Yt, Xt, out);
}

// Round 7
// 158.565 us; speedup vs baseline: 2.6800x; 1.4696x over previous
//
#include <hip/hip_runtime.h>

#define BS 64
#define TT 2048
#define NJ 24
#define ROWF 99            // 24*4 quats + 3 pos
#define BLOCK 256
#define NROWS (BS * TT)    // 131072 rows, one thread per row
#define PFD 8              // prefetch depth in joints (ring of 8 float4 per array)

// 16B load at 4B alignment (rows are 396B-strided): gfx950 handles dword-aligned
// dwordx4 in HW (may split lines).
__device__ __forceinline__ float4 ld4u(const float* __restrict__ p) {
  return *reinterpret_cast<const float4*>(p);
}

__device__ __forceinline__ void quat2mat_s(float w, float x, float y, float z,
                                           float s, float* R) {
  const float xx = s*x*x, yy = s*y*y, zz = s*z*z;
  const float xy = s*x*y, xz = s*x*z, yz = s*y*z;
  const float xw = s*x*w, yw = s*y*w, zw = s*z*w;
  R[0] = 1.0f - (yy+zz); R[1] = xy - zw;        R[2] = xz + yw;
  R[3] = xy + zw;        R[4] = 1.0f - (xx+zz); R[5] = yz - xw;
  R[6] = xz - yw;        R[7] = yz + xw;        R[8] = 1.0f - (xx+yy);
}

__device__ __forceinline__ void mm3(const float* A, const float* B, float* C) {
#pragma unroll
  for (int r = 0; r < 3; ++r) {
#pragma unroll
    for (int c = 0; c < 3; ++c) {
      C[3*r+c] = fmaf(A[3*r], B[c], fmaf(A[3*r+1], B[3+c], A[3*r+2]*B[6+c]));
    }
  }
}

// ROUND-1 STRUCTURE (best measured: 75us/dispatch): one thread per row, X and Y
// chains interleaved (2-way ILP), D = gtrY - gtrX carried per slot, no LDS, no
// inter-thread communication, no spill. ROUND-7 ADDITION: explicit 8-deep
// software prefetch ring over an INDEX-ORDER walk (topology[i] < i makes 0..23
// a valid topological order; <=3 ancestor states live -> 3 slots). Ring indices
// are all compile-time constants -> registers, never scratch.
// Slot schedule (verified liveness):
//  j : 1 2 3 4 5 6 7 8 9 10 11 12 13 14 15 16 17 18 19 20 21 22 23
//  PS: 0 0 0 1 2 0 1 2 0  1  2  0  0  0  1  2  0  2  0  2  0  2  0
//  NS: 1 2 0 1 2 0 1 2 0  1  2  1  2  0  1  2  0  2  0  2  0  2  0
__global__ __launch_bounds__(BLOCK, 2) void motion_loss_kernel(
    const float* __restrict__ Ym, const float* __restrict__ Xm,
    const float* __restrict__ Yt, const float* __restrict__ Xt,
    float* __restrict__ out) {
  const int tid = threadIdx.x;
  const size_t row = (size_t)blockIdx.x * BLOCK + tid;
  const int b = (int)(row / TT);                 // block lies in one batch (2048 % 256 == 0)
  const float* __restrict__ xr = Xm + row * ROWF;
  const float* __restrict__ yr = Ym + row * ROWF;
  const float* __restrict__ tX = Xt + (size_t)b * NJ * 3;   // uniform per block -> s_loads
  const float* __restrict__ tY = Yt + (size_t)b * NJ * 3;

  float GX[3][9], GY[3][9], D[3][3];
  float rot_acc = 0.0f, gtr_acc = 0.0f, pos_acc = 0.0f;

  // ---- prime the pipeline: pos + joints 0..7 of both arrays (18 loads in flight)
  const float4 posx = ld4u(xr + 95);   // floats [95..98]; pos = [96..98]
  const float4 posy = ld4u(yr + 95);
  float4 qx[PFD], qy[PFD];
#pragma unroll
  for (int k = 0; k < PFD; ++k) { qx[k] = ld4u(xr + 4*k); qy[k] = ld4u(yr + 4*k); }

  // ---- joint 0 (root): consume ring slot 0, refill with joint 8 ----
  {
    const float4 vx = qx[0], vy = qy[0];
    qx[0] = ld4u(xr + 4*PFD); qy[0] = ld4u(yr + 4*PFD);
    const float qqx = vx.x*vx.x + vx.y*vx.y + vx.z*vx.z + vx.w*vx.w;
    const float qqy = vy.x*vy.x + vy.y*vy.y + vy.z*vy.z + vy.w*vy.w;
    const float ix = 1.0f / fmaxf(sqrtf(qqx), 1e-12f);
    const float iy = 1.0f / fmaxf(sqrtf(qqy), 1e-12f);
    const float r0 = vy.x*iy - vx.x*ix, r1 = vy.y*iy - vx.y*ix;
    const float r2 = vy.z*iy - vx.z*ix, r3 = vy.w*iy - vx.w*ix;
    rot_acc += r0*r0 + r1*r1 + r2*r2 + r3*r3;
    quat2mat_s(vx.x, vx.y, vx.z, vx.w, 2.0f / qqx, GX[0]);
    quat2mat_s(vy.x, vy.y, vy.z, vy.w, 2.0f / qqy, GY[0]);
    D[0][0] = posy.y - posx.y; D[0][1] = posy.z - posx.z; D[0][2] = posy.w - posx.w;
    const float dd = D[0][0]*D[0][0] + D[0][1]*D[0][1] + D[0][2]*D[0][2];
    gtr_acc += dd;      // root contributes to gtr MSE
    pos_acc  = dd;      // and to the pos MSE
  }

#define JSTEP(j, PS, NS) do {                                                  \
    const float4 vx = qx[(j) & (PFD-1)], vy = qy[(j) & (PFD-1)];               \
    if ((j) + PFD < NJ) {                                                      \
      qx[(j) & (PFD-1)] = ld4u(xr + 4*((j) + PFD));                            \
      qy[(j) & (PFD-1)] = ld4u(yr + 4*((j) + PFD));                            \
    }                                                                          \
    const float qqx = vx.x*vx.x + vx.y*vx.y + vx.z*vx.z + vx.w*vx.w;           \
    const float qqy = vy.x*vy.x + vy.y*vy.y + vy.z*vy.z + vy.w*vy.w;           \
    const float ix = 1.0f / fmaxf(sqrtf(qqx), 1e-12f);                         \
    const float iy = 1.0f / fmaxf(sqrtf(qqy), 1e-12f);                         \
    const float r0 = vy.x*iy - vx.x*ix, r1 = vy.y*iy - vx.y*ix;                \
    const float r2 = vy.z*iy - vx.z*ix, r3 = vy.w*iy - vx.w*ix;                \
    rot_acc += r0*r0 + r1*r1 + r2*r2 + r3*r3;                                  \
    const float tx0 = tX[3*(j)], tx1 = tX[3*(j)+1], tx2 = tX[3*(j)+2];         \
    const float ty0 = tY[3*(j)], ty1 = tY[3*(j)+1], ty2 = tY[3*(j)+2];         \
    const float vx0 = fmaf(GX[PS][0],tx0, fmaf(GX[PS][1],tx1, GX[PS][2]*tx2)); \
    const float vx1 = fmaf(GX[PS][3],tx0, fmaf(GX[PS][4],tx1, GX[PS][5]*tx2)); \
    const float vx2 = fmaf(GX[PS][6],tx0, fmaf(GX[PS][7],tx1, GX[PS][8]*tx2)); \
    const float vy0 = fmaf(GY[PS][0],ty0, fmaf(GY[PS][1],ty1, GY[PS][2]*ty2)); \
    const float vy1 = fmaf(GY[PS][3],ty0, fmaf(GY[PS][4],ty1, GY[PS][5]*ty2)); \
    const float vy2 = fmaf(GY[PS][6],ty0, fmaf(GY[PS][7],ty1, GY[PS][8]*ty2)); \
    const float d0 = D[PS][0] + (vy0 - vx0);                                   \
    const float d1 = D[PS][1] + (vy1 - vx1);                                   \
    const float d2 = D[PS][2] + (vy2 - vx2);                                   \
    gtr_acc += d0*d0 + d1*d1 + d2*d2;                                          \
    float RX[9], RY[9], GnX[9], GnY[9];                                        \
    quat2mat_s(vx.x, vx.y, vx.z, vx.w, 2.0f / qqx, RX);                        \
    quat2mat_s(vy.x, vy.y, vy.z, vy.w, 2.0f / qqy, RY);                        \
    mm3(GX[PS], RX, GnX);                                                      \
    mm3(GY[PS], RY, GnY);                                                      \
    _Pragma("unroll")                                                          \
    for (int k = 0; k < 9; ++k) { GX[NS][k] = GnX[k]; GY[NS][k] = GnY[k]; }    \
    D[NS][0] = d0; D[NS][1] = d1; D[NS][2] = d2;                               \
  } while (0)

  JSTEP( 1, 0, 1); JSTEP( 2, 0, 2); JSTEP( 3, 0, 0);
  JSTEP( 4, 1, 1); JSTEP( 5, 2, 2); JSTEP( 6, 0, 0);
  JSTEP( 7, 1, 1); JSTEP( 8, 2, 2); JSTEP( 9, 0, 0);
  JSTEP(10, 1, 1); JSTEP(11, 2, 2);
  JSTEP(12, 0, 1); JSTEP(13, 0, 2); JSTEP(14, 0, 0);
  JSTEP(15, 1, 1); JSTEP(16, 2, 2); JSTEP(17, 0, 0);
  JSTEP(18, 2, 2); JSTEP(19, 0, 0); JSTEP(20, 2, 2);
  JSTEP(21, 0, 0); JSTEP(22, 2, 2); JSTEP(23, 0, 0);
#undef JSTEP

  const float c_rot = 1.0f / ((float)NROWS * NJ * 4);   // B1 * mean over (bs,T,24,4)
  const float c_gtr = 2.5f / ((float)NROWS * NJ * 3);   // B2 * 2.5 * mean over (bs,T,24,3)
  const float c_pos = 1.0f / ((float)NROWS * 3);        // B2 * mean over (bs,T,3)
  float contrib = c_rot * rot_acc + c_gtr * gtr_acc + c_pos * pos_acc;
#pragma unroll
  for (int o = 32; o > 0; o >>= 1) contrib += __shfl_down(contrib, o, 64);
  if ((tid & 63) == 0) atomicAdd(out, contrib);
}

extern "C" void kernel_launch(void* const* d_in, const int* in_sizes, int n_in,
                              void* d_out, int out_size, void* d_ws, size_t ws_size,
                              hipStream_t stream) {
  const float* Ym = (const float*)d_in[0];
  const float* Xm = (const float*)d_in[1];
  const float* Yt = (const float*)d_in[2];
  const float* Xt = (const float*)d_in[3];
  float* out = (float*)d_out;
  hipMemsetAsync(out, 0, sizeof(float), stream);  // graph-capturable
  motion_loss_kernel<<<NROWS / BLOCK, BLOCK, 0, stream>>>(Ym, Xm, Yt, Xt, out);
}

// Round 9
// 154.967 us; speedup vs baseline: 2.7423x; 1.0232x over previous
//
#include <hip/hip_runtime.h>

#define BS 64
#define TT 2048
#define NJ 24
#define ROWF 99            // 24*4 quats + 3 pos
#define BLOCK 128          // 1 thread per row, 128 consecutive rows per block
#define NROWS (BS * TT)    // 131072 rows
#define LSTR 20            // LDS row stride in floats (80 B: 16-aligned, 8-way-max banks)

// 16B global load at 4B alignment (rows are 396B-strided): gfx950 handles
// dword-aligned dwordx4 in HW.
__device__ __forceinline__ float4 ld4u(const float* __restrict__ p) {
  return *reinterpret_cast<const float4*>(p);
}

__device__ __forceinline__ void quat2mat_s(float w, float x, float y, float z,
                                           float s, float* R) {
  const float xx = s*x*x, yy = s*y*y, zz = s*z*z;
  const float xy = s*x*y, xz = s*x*z, yz = s*y*z;
  const float xw = s*x*w, yw = s*y*w, zw = s*z*w;
  R[0] = 1.0f - (yy+zz); R[1] = xy - zw;        R[2] = xz + yw;
  R[3] = xy + zw;        R[4] = 1.0f - (xx+zz); R[5] = yz - xw;
  R[6] = xz - yw;        R[7] = yz + xw;        R[8] = 1.0f - (xx+yy);
}

__device__ __forceinline__ void mm3(const float* A, const float* B, float* C) {
#pragma unroll
  for (int r = 0; r < 3; ++r) {
#pragma unroll
    for (int c = 0; c < 3; ++c) {
      C[3*r+c] = fmaf(A[3*r], B[c], fmaf(A[3*r+1], B[3+c], A[3*r+2]*B[6+c]));
    }
  }
}

// ROUND-7 FK (best: 66us): 1 thread/row, X+Y interleaved (2-way ILP), D = gtrY-gtrX,
// index-order walk (topology[i] < i), 3-slot liveness schedule.
// ROUND-8/9: quats arrive via a COALESCED, double-buffered LDS window pipeline:
// 6 windows x 4 joints; window w+2's global->reg loads issued at boundary w,
// reg->LDS written at boundary w+1 (T14 async split: ~1 compute window of flight
// time). Staging: 4 lanes cover each row's 64 B chunk (coalesced) vs the old
// per-lane divergent walk (~64-80 lines/wave-instr). LDS rows padded to 80 B.
__global__ __launch_bounds__(BLOCK, 2) void motion_loss_kernel(
    const float* __restrict__ Ym, const float* __restrict__ Xm,
    const float* __restrict__ Yt, const float* __restrict__ Xt,
    float* __restrict__ out) {
  __shared__ __align__(16) float lX[2][BLOCK * LSTR];  // 2 x 10240 B
  __shared__ __align__(16) float lY[2][BLOCK * LSTR];  // total 40 KB -> 4 blocks/CU

  const int t = threadIdx.x;
  const size_t row0 = (size_t)blockIdx.x * BLOCK;
  const int b = blockIdx.x >> 4;                 // 16 blocks per batch (2048/128)
  const float* __restrict__ xt = Xm + row0 * ROWF;   // tile bases (contiguous slab)
  const float* __restrict__ yt = Ym + row0 * ROWF;
  const float* __restrict__ tX = Xt + (size_t)b * NJ * 3;  // uniform -> s_loads
  const float* __restrict__ tY = Yt + (size_t)b * NJ * 3;

  // pos of own row: 2 direct (divergent) loads, issued first, consumed in window 0
  const float4 posx = ld4u(xt + t * ROWF + 95);  // floats [95..98]; pos = [96..98]
  const float4 posy = ld4u(yt + t * ROWF + 95);

  float4 sx[4], sy[4];   // staging regs: 512 float4 per array per window / 128 thr

  // stage window w: thread t handles chunks l = t + k*128; row r=l>>2, slot s=l&3
#define STAGE_ISSUE(w) do {                                                    \
    _Pragma("unroll")                                                          \
    for (int k = 0; k < 4; ++k) {                                              \
      const int l = t + k * BLOCK, r = l >> 2, s = l & 3;                      \
      sx[k] = ld4u(xt + r * ROWF + (w) * 16 + s * 4);                          \
      sy[k] = ld4u(yt + r * ROWF + (w) * 16 + s * 4);                          \
    }                                                                          \
  } while (0)

#define STAGE_WRITE(w) do {                                                    \
    _Pragma("unroll")                                                          \
    for (int k = 0; k < 4; ++k) {                                              \
      const int l = t + k * BLOCK, r = l >> 2, s = l & 3;                      \
      *reinterpret_cast<float4*>(&lX[(w) & 1][r * LSTR + s * 4]) = sx[k];      \
      *reinterpret_cast<float4*>(&lY[(w) & 1][r * LSTR + s * 4]) = sy[k];      \
    }                                                                          \
  } while (0)

  STAGE_ISSUE(0);
  STAGE_WRITE(0);          // implicit vmcnt wait on sx/sy use
  STAGE_ISSUE(1);
  __syncthreads();         // buf0 (W0) visible

  float GX[3][9], GY[3][9], D[3][3];
  float rot_acc = 0.0f, gtr_acc = 0.0f, pos_acc = 0.0f;

  // ---- joint 0 (root): window 0, slot 0 ----
  {
    const float4 vx = *reinterpret_cast<const float4*>(&lX[0][t * LSTR]);
    const float4 vy = *reinterpret_cast<const float4*>(&lY[0][t * LSTR]);
    const float qqx = vx.x*vx.x + vx.y*vx.y + vx.z*vx.z + vx.w*vx.w;
    const float qqy = vy.x*vy.x + vy.y*vy.y + vy.z*vy.z + vy.w*vy.w;
    const float ix = 1.0f / fmaxf(sqrtf(qqx), 1e-12f);
    const float iy = 1.0f / fmaxf(sqrtf(qqy), 1e-12f);
    const float r0 = vy.x*iy - vx.x*ix, r1 = vy.y*iy - vx.y*ix;
    const float r2 = vy.z*iy - vx.z*ix, r3 = vy.w*iy - vx.w*ix;
    rot_acc += r0*r0 + r1*r1 + r2*r2 + r3*r3;
    quat2mat_s(vx.x, vx.y, vx.z, vx.w, 2.0f / qqx, GX[0]);
    quat2mat_s(vy.x, vy.y, vy.z, vy.w, 2.0f / qqy, GY[0]);
    D[0][0] = posy.y - posx.y; D[0][1] = posy.z - posx.z; D[0][2] = posy.w - posx.w;
    const float dd = D[0][0]*D[0][0] + D[0][1]*D[0][1] + D[0][2]*D[0][2];
    gtr_acc += dd;      // root contributes to gtr MSE
    pos_acc  = dd;      // and to the pos MSE
  }

#define JSTEP(j, PS, NS) do {                                                  \
    const float4 vx = *reinterpret_cast<const float4*>(                        \
        &lX[((j) >> 2) & 1][t * LSTR + ((j) & 3) * 4]);                        \
    const float4 vy = *reinterpret_cast<const float4*>(                        \
        &lY[((j) >> 2) & 1][t * LSTR + ((j) & 3) * 4]);                        \
    const float qqx = vx.x*vx.x + vx.y*vx.y + vx.z*vx.z + vx.w*vx.w;           \
    const float qqy = vy.x*vy.x + vy.y*vy.y + vy.z*vy.z + vy.w*vy.w;           \
    const float ix = 1.0f / fmaxf(sqrtf(qqx), 1e-12f);                         \
    const float iy = 1.0f / fmaxf(sqrtf(qqy), 1e-12f);                         \
    const float r0 = vy.x*iy - vx.x*ix, r1 = vy.y*iy - vx.y*ix;                \
    const float r2 = vy.z*iy - vx.z*ix, r3 = vy.w*iy - vx.w*ix;                \
    rot_acc += r0*r0 + r1*r1 + r2*r2 + r3*r3;                                  \
    const float tx0 = tX[3*(j)], tx1 = tX[3*(j)+1], tx2 = tX[3*(j)+2];         \
    const float ty0 = tY[3*(j)], ty1 = tY[3*(j)+1], ty2 = tY[3*(j)+2];         \
    const float vx0 = fmaf(GX[PS][0],tx0, fmaf(GX[PS][1],tx1, GX[PS][2]*tx2)); \
    const float vx1 = fmaf(GX[PS][3],tx0, fmaf(GX[PS][4],tx1, GX[PS][5]*tx2)); \
    const float vx2 = fmaf(GX[PS][6],tx0, fmaf(GX[PS][7],tx1, GX[PS][8]*tx2)); \
    const float vy0 = fmaf(GY[PS][0],ty0, fmaf(GY[PS][1],ty1, GY[PS][2]*ty2)); \
    const float vy1 = fmaf(GY[PS][3],ty0, fmaf(GY[PS][4],ty1, GY[PS][5]*ty2)); \
    const float vy2 = fmaf(GY[PS][6],ty0, fmaf(GY[PS][7],ty1, GY[PS][8]*ty2)); \
    const float d0 = D[PS][0] + (vy0 - vx0);                                   \
    const float d1 = D[PS][1] + (vy1 - vx1);                                   \
    const float d2 = D[PS][2] + (vy2 - vx2);                                   \
    gtr_acc += d0*d0 + d1*d1 + d2*d2;                                          \
    float RX[9], RY[9], GnX[9], GnY[9];                                        \
    quat2mat_s(vx.x, vx.y, vx.z, vx.w, 2.0f / qqx, RX);                        \
    quat2mat_s(vy.x, vy.y, vy.z, vy.w, 2.0f / qqy, RY);                        \
    mm3(GX[PS], RX, GnX);                                                      \
    mm3(GY[PS], RY, GnY);                                                      \
    _Pragma("unroll")                                                          \
    for (int k = 0; k < 9; ++k) { GX[NS][k] = GnX[k]; GY[NS][k] = GnY[k]; }    \
    D[NS][0] = d0; D[NS][1] = d1; D[NS][2] = d2;                               \
  } while (0)

  // boundary after window w: all threads done reading buf[(w+1)&1]'s old tenant
#define BOUNDARY(wnext, wissue) do {                                           \
    __syncthreads();                                                           \
    STAGE_WRITE(wnext);                                                        \
    if ((wissue) < 6) STAGE_ISSUE(wissue);                                     \
    __syncthreads();                                                           \
  } while (0)

  // W0: joints 0..3 (root above)
  JSTEP( 1, 0, 1); JSTEP( 2, 0, 2); JSTEP( 3, 0, 0);
  BOUNDARY(1, 2);
  // W1: 4..7
  JSTEP( 4, 1, 1); JSTEP( 5, 2, 2); JSTEP( 6, 0, 0); JSTEP( 7, 1, 1);
  BOUNDARY(2, 3);
  // W2: 8..11
  JSTEP( 8, 2, 2); JSTEP( 9, 0, 0); JSTEP(10, 1, 1); JSTEP(11, 2, 2);
  BOUNDARY(3, 4);
  // W3: 12..15
  JSTEP(12, 0, 1); JSTEP(13, 0, 2); JSTEP(14, 0, 0); JSTEP(15, 1, 1);
  BOUNDARY(4, 5);
  // W4: 16..19
  JSTEP(16, 2, 2); JSTEP(17, 0, 0); JSTEP(18, 2, 2); JSTEP(19, 0, 0);
  BOUNDARY(5, 6);
  // W5: 20..23
  JSTEP(20, 2, 2); JSTEP(21, 0, 0); JSTEP(22, 2, 2); JSTEP(23, 0, 0);
#undef JSTEP
#undef BOUNDARY
#undef STAGE_ISSUE
#undef STAGE_WRITE

  const float c_rot = 1.0f / ((float)NROWS * NJ * 4);   // B1 * mean over (bs,T,24,4)
  const float c_gtr = 2.5f / ((float)NROWS * NJ * 3);   // B2 * 2.5 * mean over (bs,T,24,3)
  const float c_pos = 1.0f / ((float)NROWS * 3);        // B2 * mean over (bs,T,3)
  float contrib = c_rot * rot_acc + c_gtr * gtr_acc + c_pos * pos_acc;
#pragma unroll
  for (int o = 32; o > 0; o >>= 1) contrib += __shfl_down(contrib, o, 64);
  if ((t & 63) == 0) atomicAdd(out, contrib);
}

extern "C" void kernel_launch(void* const* d_in, const int* in_sizes, int n_in,
                              void* d_out, int out_size, void* d_ws, size_t ws_size,
                              hipStream_t stream) {
  const float* Ym = (const float*)d_in[0];
  const float* Xm = (const float*)d_in[1];
  const float* Yt = (const float*)d_in[2];
  const float* Xt = (const float*)d_in[3];
  float* out = (float*)d_out;
  hipMemsetAsync(out, 0, sizeof(float), stream);  // graph-capturable
  motion_loss_kernel<<<NROWS / BLOCK, BLOCK, 0, stream>>>(Ym, Xm, Yt, Xt, out);
}

// Round 10
// 153.277 us; speedup vs baseline: 2.7725x; 1.0110x over previous
//
#include <hip/hip_runtime.h>

#define BS 64
#define TT 2048
#define NJ 24
#define ROWF 99            // 24*4 quats + 3 pos
#define BLOCK 64           // ONE wave per block: wave-private LDS, zero barriers
#define NROWS (BS * TT)    // 131072 rows
#define LSTR 20            // LDS row stride in floats (80 B)

// 16B global load at 4B alignment (rows are 396B-strided): gfx950 handles
// dword-aligned dwordx4 in HW.
__device__ __forceinline__ float4 ld4u(const float* __restrict__ p) {
  return *reinterpret_cast<const float4*>(p);
}

__device__ __forceinline__ void quat2mat_s(float w, float x, float y, float z,
                                           float s, float* R) {
  const float xx = s*x*x, yy = s*y*y, zz = s*z*z;
  const float xy = s*x*y, xz = s*x*z, yz = s*y*z;
  const float xw = s*x*w, yw = s*y*w, zw = s*z*w;
  R[0] = 1.0f - (yy+zz); R[1] = xy - zw;        R[2] = xz + yw;
  R[3] = xy + zw;        R[4] = 1.0f - (xx+zz); R[5] = yz - xw;
  R[6] = xz - yw;        R[7] = yz + xw;        R[8] = 1.0f - (xx+yy);
}

__device__ __forceinline__ void mm3(const float* A, const float* B, float* C) {
#pragma unroll
  for (int r = 0; r < 3; ++r) {
#pragma unroll
    for (int c = 0; c < 3; ++c) {
      C[3*r+c] = fmaf(A[3*r], B[c], fmaf(A[3*r+1], B[3+c], A[3*r+2]*B[6+c]));
    }
  }
}

// ROUND-10: round-9 pipeline made WAVE-PRIVATE (BLOCK=64, one wave per block,
// LDS double-buffer owned by the wave -> NO __syncthreads; ordering is the
// wave's own vmcnt/lgkmcnt) + trans-pipe trim: one rsqrt replaces sqrt+2*rcp
// per quat ( ix = rsqrt(max(qq,1e-24)) == 1/max(sqrt(qq),1e-12); s = 2*ix*ix
// == 2/qq to ~2ulp, reference's two_s is unclamped ).
// FK core unchanged (best-measured structure): 1 thread/row, X+Y interleaved
// (2-way ILP), D = gtrY-gtrX, index-order walk, 3-slot liveness schedule.
__global__ __launch_bounds__(BLOCK, 2) void motion_loss_kernel(
    const float* __restrict__ Ym, const float* __restrict__ Xm,
    const float* __restrict__ Yt, const float* __restrict__ Xt,
    float* __restrict__ out) {
  __shared__ __align__(16) float lX[2][BLOCK * LSTR];  // 2 x 5120 B
  __shared__ __align__(16) float lY[2][BLOCK * LSTR];  // total 20 KB -> 8 blocks/CU

  const int t = threadIdx.x;
  const size_t row0 = (size_t)blockIdx.x * BLOCK;
  const int b = blockIdx.x >> 5;                 // 32 blocks per batch (2048/64)
  const float* __restrict__ xt = Xm + row0 * ROWF;   // wave's contiguous slab
  const float* __restrict__ yt = Ym + row0 * ROWF;
  const float* __restrict__ tX = Xt + (size_t)b * NJ * 3;  // uniform -> s_loads
  const float* __restrict__ tY = Yt + (size_t)b * NJ * 3;

  // pos of own row: 2 direct loads, issued first, consumed in window 0
  const float4 posx = ld4u(xt + t * ROWF + 95);  // floats [95..98]; pos = [96..98]
  const float4 posy = ld4u(yt + t * ROWF + 95);

  float4 sx[4], sy[4];   // staging regs: 256 chunks per array per window / 64 lanes

  // window w covers joints 4w..4w+3 = floats [w*16, w*16+16) of each row.
  // chunks l = t + k*64; row r = l>>2 (0..63), slot s = l&3. Lanes 4m..4m+3
  // cover one row's 64 B contiguous -> coalesced 64 B segments.
#define STAGE_ISSUE(w) do {                                                    \
    _Pragma("unroll")                                                          \
    for (int k = 0; k < 4; ++k) {                                              \
      const int l = t + k * BLOCK, r = l >> 2, s = l & 3;                      \
      sx[k] = ld4u(xt + r * ROWF + (w) * 16 + s * 4);                          \
      sy[k] = ld4u(yt + r * ROWF + (w) * 16 + s * 4);                          \
    }                                                                          \
  } while (0)

#define STAGE_WRITE(w) do {                                                    \
    _Pragma("unroll")                                                          \
    for (int k = 0; k < 4; ++k) {                                              \
      const int l = t + k * BLOCK, r = l >> 2, s = l & 3;                      \
      *reinterpret_cast<float4*>(&lX[(w) & 1][r * LSTR + s * 4]) = sx[k];      \
      *reinterpret_cast<float4*>(&lY[(w) & 1][r * LSTR + s * 4]) = sy[k];      \
    }                                                                          \
  } while (0)

  STAGE_ISSUE(0);
  STAGE_WRITE(0);          // vmcnt wait on sx/sy (compiler-inserted)
  STAGE_ISSUE(1);          // window 1 in flight across window-0 compute

  float GX[3][9], GY[3][9], D[3][3];
  float rot_acc = 0.0f, gtr_acc = 0.0f, pos_acc = 0.0f;

  // ---- joint 0 (root): window 0, slot 0 ----
  {
    const float4 vx = *reinterpret_cast<const float4*>(&lX[0][t * LSTR]);
    const float4 vy = *reinterpret_cast<const float4*>(&lY[0][t * LSTR]);
    const float qqx = vx.x*vx.x + vx.y*vx.y + vx.z*vx.z + vx.w*vx.w;
    const float qqy = vy.x*vy.x + vy.y*vy.y + vy.z*vy.z + vy.w*vy.w;
    const float ix = rsqrtf(fmaxf(qqx, 1e-24f));   // == 1/max(sqrt(qqx),1e-12)
    const float iy = rsqrtf(fmaxf(qqy, 1e-24f));
    const float r0 = vy.x*iy - vx.x*ix, r1 = vy.y*iy - vx.y*ix;
    const float r2 = vy.z*iy - vx.z*ix, r3 = vy.w*iy - vx.w*ix;
    rot_acc += r0*r0 + r1*r1 + r2*r2 + r3*r3;
    quat2mat_s(vx.x, vx.y, vx.z, vx.w, 2.0f*ix*ix, GX[0]);  // s = 2/qq (~2ulp)
    quat2mat_s(vy.x, vy.y, vy.z, vy.w, 2.0f*iy*iy, GY[0]);
    D[0][0] = posy.y - posx.y; D[0][1] = posy.z - posx.z; D[0][2] = posy.w - posx.w;
    const float dd = D[0][0]*D[0][0] + D[0][1]*D[0][1] + D[0][2]*D[0][2];
    gtr_acc += dd;      // root contributes to gtr MSE
    pos_acc  = dd;      // and to the pos MSE
  }

#define JSTEP(j, PS, NS) do {                                                  \
    const float4 vx = *reinterpret_cast<const float4*>(                        \
        &lX[((j) >> 2) & 1][t * LSTR + ((j) & 3) * 4]);                        \
    const float4 vy = *reinterpret_cast<const float4*>(                        \
        &lY[((j) >> 2) & 1][t * LSTR + ((j) & 3) * 4]);                        \
    const float qqx = vx.x*vx.x + vx.y*vx.y + vx.z*vx.z + vx.w*vx.w;           \
    const float qqy = vy.x*vy.x + vy.y*vy.y + vy.z*vy.z + vy.w*vy.w;           \
    const float ix = rsqrtf(fmaxf(qqx, 1e-24f));                               \
    const float iy = rsqrtf(fmaxf(qqy, 1e-24f));                               \
    const float r0 = vy.x*iy - vx.x*ix, r1 = vy.y*iy - vx.y*ix;                \
    const float r2 = vy.z*iy - vx.z*ix, r3 = vy.w*iy - vx.w*ix;                \
    rot_acc += r0*r0 + r1*r1 + r2*r2 + r3*r3;                                  \
    const float tx0 = tX[3*(j)], tx1 = tX[3*(j)+1], tx2 = tX[3*(j)+2];         \
    const float ty0 = tY[3*(j)], ty1 = tY[3*(j)+1], ty2 = tY[3*(j)+2];         \
    const float vx0 = fmaf(GX[PS][0],tx0, fmaf(GX[PS][1],tx1, GX[PS][2]*tx2)); \
    const float vx1 = fmaf(GX[PS][3],tx0, fmaf(GX[PS][4],tx1, GX[PS][5]*tx2)); \
    const float vx2 = fmaf(GX[PS][6],tx0, fmaf(GX[PS][7],tx1, GX[PS][8]*tx2)); \
    const float vy0 = fmaf(GY[PS][0],ty0, fmaf(GY[PS][1],ty1, GY[PS][2]*ty2)); \
    const float vy1 = fmaf(GY[PS][3],ty0, fmaf(GY[PS][4],ty1, GY[PS][5]*ty2)); \
    const float vy2 = fmaf(GY[PS][6],ty0, fmaf(GY[PS][7],ty1, GY[PS][8]*ty2)); \
    const float d0 = D[PS][0] + (vy0 - vx0);                                   \
    const float d1 = D[PS][1] + (vy1 - vx1);                                   \
    const float d2 = D[PS][2] + (vy2 - vx2);                                   \
    gtr_acc += d0*d0 + d1*d1 + d2*d2;                                          \
    float RX[9], RY[9], GnX[9], GnY[9];                                        \
    quat2mat_s(vx.x, vx.y, vx.z, vx.w, 2.0f*ix*ix, RX);                        \
    quat2mat_s(vy.x, vy.y, vy.z, vy.w, 2.0f*iy*iy, RY);                        \
    mm3(GX[PS], RX, GnX);                                                      \
    mm3(GY[PS], RY, GnY);                                                      \
    _Pragma("unroll")                                                          \
    for (int k = 0; k < 9; ++k) { GX[NS][k] = GnX[k]; GY[NS][k] = GnY[k]; }    \
    D[NS][0] = d0; D[NS][1] = d1; D[NS][2] = d2;                               \
  } while (0)

  // boundary after window w (wave-private: no barriers; vmcnt/lgkmcnt order us)
#define BOUNDARY(wnext, wissue) do {                                           \
    STAGE_WRITE(wnext);                                                        \
    if ((wissue) < 6) STAGE_ISSUE(wissue);                                     \
  } while (0)

  // W0: joints 0..3 (root above)
  JSTEP( 1, 0, 1); JSTEP( 2, 0, 2); JSTEP( 3, 0, 0);
  BOUNDARY(1, 2);
  // W1: 4..7
  JSTEP( 4, 1, 1); JSTEP( 5, 2, 2); JSTEP( 6, 0, 0); JSTEP( 7, 1, 1);
  BOUNDARY(2, 3);
  // W2: 8..11
  JSTEP( 8, 2, 2); JSTEP( 9, 0, 0); JSTEP(10, 1, 1); JSTEP(11, 2, 2);
  BOUNDARY(3, 4);
  // W3: 12..15
  JSTEP(12, 0, 1); JSTEP(13, 0, 2); JSTEP(14, 0, 0); JSTEP(15, 1, 1);
  BOUNDARY(4, 5);
  // W4: 16..19
  JSTEP(16, 2, 2); JSTEP(17, 0, 0); JSTEP(18, 2, 2); JSTEP(19, 0, 0);
  BOUNDARY(5, 6);
  // W5: 20..23
  JSTEP(20, 2, 2); JSTEP(21, 0, 0); JSTEP(22, 2, 2); JSTEP(23, 0, 0);
#undef JSTEP
#undef BOUNDARY
#undef STAGE_ISSUE
#undef STAGE_WRITE

  const float c_rot = 1.0f / ((float)NROWS * NJ * 4);   // B1 * mean over (bs,T,24,4)
  const float c_gtr = 2.5f / ((float)NROWS * NJ * 3);   // B2 * 2.5 * mean over (bs,T,24,3)
  const float c_pos = 1.0f / ((float)NROWS * 3);        // B2 * mean over (bs,T,3)
  float contrib = c_rot * rot_acc + c_gtr * gtr_acc + c_pos * pos_acc;
#pragma unroll
  for (int o = 32; o > 0; o >>= 1) contrib += __shfl_down(contrib, o, 64);
  if (t == 0) atomicAdd(out, contrib);
}

extern "C" void kernel_launch(void* const* d_in, const int* in_sizes, int n_in,
                              void* d_out, int out_size, void* d_ws, size_t ws_size,
                              hipStream_t stream) {
  const float* Ym = (const float*)d_in[0];
  const float* Xm = (const float*)d_in[1];
  const float* Yt = (const float*)d_in[2];
  const float* Xt = (const float*)d_in[3];
  float* out = (float*)d_out;
  hipMemsetAsync(out, 0, sizeof(float), stream);  // graph-capturable
  motion_loss_kernel<<<NROWS / BLOCK, BLOCK, 0, stream>>>(Ym, Xm, Yt, Xt, out);
}

// Round 11
// 153.265 us; speedup vs baseline: 2.7727x; 1.0001x over previous
//
#include <hip/hip_runtime.h>

#define BS 64
#define TT 2048
#define NJ 24
#define ROWF 99            // 24*4 quats + 3 pos
#define BLOCK 64           // ONE wave per block: wave-private LDS, zero barriers
#define NROWS (BS * TT)    // 131072 rows
#define LSTR 20            // LDS row stride in floats (80 B)

// 16B global load at 4B alignment: gfx950 handles dword-aligned dwordx4 in HW.
__device__ __forceinline__ float4 ld4u(const float* __restrict__ p) {
  return *reinterpret_cast<const float4*>(p);
}

__device__ __forceinline__ void quat2mat_s(float w, float x, float y, float z,
                                           float s, float* R) {
  const float xx = s*x*x, yy = s*y*y, zz = s*z*z;
  const float xy = s*x*y, xz = s*x*z, yz = s*y*z;
  const float xw = s*x*w, yw = s*y*w, zw = s*z*w;
  R[0] = 1.0f - (yy+zz); R[1] = xy - zw;        R[2] = xz + yw;
  R[3] = xy + zw;        R[4] = 1.0f - (xx+zz); R[5] = yz - xw;
  R[6] = xz - yw;        R[7] = yz + xw;        R[8] = 1.0f - (xx+yy);
}

__device__ __forceinline__ void mm3(const float* A, const float* B, float* C) {
#pragma unroll
  for (int r = 0; r < 3; ++r) {
#pragma unroll
    for (int c = 0; c < 3; ++c) {
      C[3*r+c] = fmaf(A[3*r], B[c], fmaf(A[3*r+1], B[3+c], A[3*r+2]*B[6+c]));
    }
  }
}

// ROUND-11: round-10 wave-private pipeline with the load schedule fixed for
// CONTINUOUS flight. Diagnosis: burst-8-loads + vmcnt(0)-drain per boundary
// gives ~30% load-pipe duty cycle -> 2 TB/s (= measured). Fix: (a) two staging
// register banks (even/odd windows) so the pre-write wait is an implicit
// vmcnt(8), never a full drain; (b) window w+2's 8 loads are issued spread
// 2-per-JSTEP through window w's compute -> issuance is continuous, flight
// depth oscillates 8..16 loads (8-16 KB/wave) instead of 0..8.
// FK core unchanged (best-measured): 1 thread/row, X+Y interleaved, D=gtrY-gtrX,
// index-order walk, 3-slot liveness, rsqrt-based normalization.
__global__ __launch_bounds__(BLOCK, 2) void motion_loss_kernel(
    const float* __restrict__ Ym, const float* __restrict__ Xm,
    const float* __restrict__ Yt, const float* __restrict__ Xt,
    float* __restrict__ out) {
  __shared__ __align__(16) float lX[2][BLOCK * LSTR];  // 2 x 5120 B
  __shared__ __align__(16) float lY[2][BLOCK * LSTR];  // total 20 KB -> 8 blocks/CU

  const int t = threadIdx.x;
  const size_t row0 = (size_t)blockIdx.x * BLOCK;
  const int b = blockIdx.x >> 5;                 // 32 blocks per batch (2048/64)
  const float* __restrict__ xt = Xm + row0 * ROWF;   // wave's contiguous slab
  const float* __restrict__ yt = Ym + row0 * ROWF;
  const float* __restrict__ tX = Xt + (size_t)b * NJ * 3;  // uniform -> s_loads
  const float* __restrict__ tY = Yt + (size_t)b * NJ * 3;

  // pos of own row: issued FIRST (oldest in queue), consumed at root
  const float4 posx = ld4u(xt + t * ROWF + 95);  // floats [95..98]; pos = [96..98]
  const float4 posy = ld4u(yt + t * ROWF + 95);

  // per-lane chunk geometry: lane t covers chunks l = t + 64k (k=0..3):
  // row r=l>>2, slot s=l&3. Window w adds a compile-time offset of w*64 B.
  const float* bx[4]; const float* by[4];
#pragma unroll
  for (int k = 0; k < 4; ++k) {
    const int l = t + k * BLOCK, r = l >> 2, s = l & 3;
    bx[k] = xt + r * ROWF + s * 4;
    by[k] = yt + r * ROWF + s * 4;
  }

  float4 sxA[4], syA[4], sxB[4], syB[4];   // two staging banks (even/odd window)

#define ISSUE2(w, BX, BY, k) do {                                              \
    BX[k] = ld4u(bx[k] + (w) * 16);                                            \
    BY[k] = ld4u(by[k] + (w) * 16);                                            \
  } while (0)

#define WRITE_BANK(w, BX, BY) do {                                             \
    _Pragma("unroll")                                                          \
    for (int k = 0; k < 4; ++k) {                                              \
      const int l = t + k * BLOCK, r = l >> 2, s = l & 3;                      \
      *reinterpret_cast<float4*>(&lX[(w) & 1][r * LSTR + s * 4]) = BX[k];      \
      *reinterpret_cast<float4*>(&lY[(w) & 1][r * LSTR + s * 4]) = BY[k];      \
    }                                                                          \
  } while (0)

  // prologue: W0 -> A, W1 -> B (16 loads + 2 pos in flight), write W0
  ISSUE2(0, sxA, syA, 0); ISSUE2(0, sxA, syA, 1);
  ISSUE2(0, sxA, syA, 2); ISSUE2(0, sxA, syA, 3);
  ISSUE2(1, sxB, syB, 0); ISSUE2(1, sxB, syB, 1);
  ISSUE2(1, sxB, syB, 2); ISSUE2(1, sxB, syB, 3);
  WRITE_BANK(0, sxA, syA);   // implicit vmcnt(8): waits A only, B stays in flight

  float GX[3][9], GY[3][9], D[3][3];
  float rot_acc = 0.0f, gtr_acc = 0.0f, pos_acc = 0.0f;

  // ---- joint 0 (root): window 0, slot 0 ----
  {
    const float4 vx = *reinterpret_cast<const float4*>(&lX[0][t * LSTR]);
    const float4 vy = *reinterpret_cast<const float4*>(&lY[0][t * LSTR]);
    const float qqx = vx.x*vx.x + vx.y*vx.y + vx.z*vx.z + vx.w*vx.w;
    const float qqy = vy.x*vy.x + vy.y*vy.y + vy.z*vy.z + vy.w*vy.w;
    const float ix = rsqrtf(fmaxf(qqx, 1e-24f));   // == 1/max(sqrt(qqx),1e-12)
    const float iy = rsqrtf(fmaxf(qqy, 1e-24f));
    const float r0 = vy.x*iy - vx.x*ix, r1 = vy.y*iy - vx.y*ix;
    const float r2 = vy.z*iy - vx.z*ix, r3 = vy.w*iy - vx.w*ix;
    rot_acc += r0*r0 + r1*r1 + r2*r2 + r3*r3;
    quat2mat_s(vx.x, vx.y, vx.z, vx.w, 2.0f*ix*ix, GX[0]);  // s = 2/qq (~2ulp)
    quat2mat_s(vy.x, vy.y, vy.z, vy.w, 2.0f*iy*iy, GY[0]);
    D[0][0] = posy.y - posx.y; D[0][1] = posy.z - posx.z; D[0][2] = posy.w - posx.w;
    const float dd = D[0][0]*D[0][0] + D[0][1]*D[0][1] + D[0][2]*D[0][2];
    gtr_acc += dd;      // root contributes to gtr MSE
    pos_acc  = dd;      // and to the pos MSE
  }

#define JSTEP(j, PS, NS) do {                                                  \
    const float4 vx = *reinterpret_cast<const float4*>(                        \
        &lX[((j) >> 2) & 1][t * LSTR + ((j) & 3) * 4]);                        \
    const float4 vy = *reinterpret_cast<const float4*>(                        \
        &lY[((j) >> 2) & 1][t * LSTR + ((j) & 3) * 4]);                        \
    const float qqx = vx.x*vx.x + vx.y*vx.y + vx.z*vx.z + vx.w*vx.w;           \
    const float qqy = vy.x*vy.x + vy.y*vy.y + vy.z*vy.z + vy.w*vy.w;           \
    const float ix = rsqrtf(fmaxf(qqx, 1e-24f));                               \
    const float iy = rsqrtf(fmaxf(qqy, 1e-24f));                               \
    const float r0 = vy.x*iy - vx.x*ix, r1 = vy.y*iy - vx.y*ix;                \
    const float r2 = vy.z*iy - vx.z*ix, r3 = vy.w*iy - vx.w*ix;                \
    rot_acc += r0*r0 + r1*r1 + r2*r2 + r3*r3;                                  \
    const float tx0 = tX[3*(j)], tx1 = tX[3*(j)+1], tx2 = tX[3*(j)+2];         \
    const float ty0 = tY[3*(j)], ty1 = tY[3*(j)+1], ty2 = tY[3*(j)+2];         \
    const float vx0 = fmaf(GX[PS][0],tx0, fmaf(GX[PS][1],tx1, GX[PS][2]*tx2)); \
    const float vx1 = fmaf(GX[PS][3],tx0, fmaf(GX[PS][4],tx1, GX[PS][5]*tx2)); \
    const float vx2 = fmaf(GX[PS][6],tx0, fmaf(GX[PS][7],tx1, GX[PS][8]*tx2)); \
    const float vy0 = fmaf(GY[PS][0],ty0, fmaf(GY[PS][1],ty1, GY[PS][2]*ty2)); \
    const float vy1 = fmaf(GY[PS][3],ty0, fmaf(GY[PS][4],ty1, GY[PS][5]*ty2)); \
    const float vy2 = fmaf(GY[PS][6],ty0, fmaf(GY[PS][7],ty1, GY[PS][8]*ty2)); \
    const float d0 = D[PS][0] + (vy0 - vx0);                                   \
    const float d1 = D[PS][1] + (vy1 - vx1);                                   \
    const float d2 = D[PS][2] + (vy2 - vx2);                                   \
    gtr_acc += d0*d0 + d1*d1 + d2*d2;                                          \
    float RX[9], RY[9], GnX[9], GnY[9];                                        \
    quat2mat_s(vx.x, vx.y, vx.z, vx.w, 2.0f*ix*ix, RX);                        \
    quat2mat_s(vy.x, vy.y, vy.z, vy.w, 2.0f*iy*iy, RY);                        \
    mm3(GX[PS], RX, GnX);                                                      \
    mm3(GY[PS], RY, GnY);                                                      \
    _Pragma("unroll")                                                          \
    for (int k = 0; k < 9; ++k) { GX[NS][k] = GnX[k]; GY[NS][k] = GnY[k]; }    \
    D[NS][0] = d0; D[NS][1] = d1; D[NS][2] = d2;                               \
  } while (0)

  // --- W0 compute (joints 0..3): issue W2 -> A, spread 1 ISSUE2 per JSTEP
  /* root above */      ISSUE2(2, sxA, syA, 0);
  JSTEP( 1, 0, 1);      ISSUE2(2, sxA, syA, 1);
  JSTEP( 2, 0, 2);      ISSUE2(2, sxA, syA, 2);
  JSTEP( 3, 0, 0);      ISSUE2(2, sxA, syA, 3);
  WRITE_BANK(1, sxB, syB);     // vmcnt(8): waits B (issued in prologue)
  // --- W1 (4..7): issue W3 -> B
  JSTEP( 4, 1, 1);      ISSUE2(3, sxB, syB, 0);
  JSTEP( 5, 2, 2);      ISSUE2(3, sxB, syB, 1);
  JSTEP( 6, 0, 0);      ISSUE2(3, sxB, syB, 2);
  JSTEP( 7, 1, 1);      ISSUE2(3, sxB, syB, 3);
  WRITE_BANK(2, sxA, syA);     // vmcnt(8): waits A (W2, issued through W0)
  // --- W2 (8..11): issue W4 -> A
  JSTEP( 8, 2, 2);      ISSUE2(4, sxA, syA, 0);
  JSTEP( 9, 0, 0);      ISSUE2(4, sxA, syA, 1);
  JSTEP(10, 1, 1);      ISSUE2(4, sxA, syA, 2);
  JSTEP(11, 2, 2);      ISSUE2(4, sxA, syA, 3);
  WRITE_BANK(3, sxB, syB);     // waits B (W3)
  // --- W3 (12..15): issue W5 -> B
  JSTEP(12, 0, 1);      ISSUE2(5, sxB, syB, 0);
  JSTEP(13, 0, 2);      ISSUE2(5, sxB, syB, 1);
  JSTEP(14, 0, 0);      ISSUE2(5, sxB, syB, 2);
  JSTEP(15, 1, 1);      ISSUE2(5, sxB, syB, 3);
  WRITE_BANK(4, sxA, syA);     // waits A (W4)
  // --- W4 (16..19): no more issues
  JSTEP(16, 2, 2); JSTEP(17, 0, 0); JSTEP(18, 2, 2); JSTEP(19, 0, 0);
  WRITE_BANK(5, sxB, syB);     // waits B (W5)
  // --- W5 (20..23)
  JSTEP(20, 2, 2); JSTEP(21, 0, 0); JSTEP(22, 2, 2); JSTEP(23, 0, 0);
#undef JSTEP
#undef ISSUE2
#undef WRITE_BANK

  const float c_rot = 1.0f / ((float)NROWS * NJ * 4);   // B1 * mean over (bs,T,24,4)
  const float c_gtr = 2.5f / ((float)NROWS * NJ * 3);   // B2 * 2.5 * mean over (bs,T,24,3)
  const float c_pos = 1.0f / ((float)NROWS * 3);        // B2 * mean over (bs,T,3)
  float contrib = c_rot * rot_acc + c_gtr * gtr_acc + c_pos * pos_acc;
#pragma unroll
  for (int o = 32; o > 0; o >>= 1) contrib += __shfl_down(contrib, o, 64);
  if (t == 0) atomicAdd(out, contrib);
}

extern "C" void kernel_launch(void* const* d_in, const int* in_sizes, int n_in,
                              void* d_out, int out_size, void* d_ws, size_t ws_size,
                              hipStream_t stream) {
  const float* Ym = (const float*)d_in[0];
  const float* Xm = (const float*)d_in[1];
  const float* Yt = (const float*)d_in[2];
  const float* Xt = (const float*)d_in[3];
  float* out = (float*)d_out;
  hipMemsetAsync(out, 0, sizeof(float), stream);  // graph-capturable
  motion_loss_kernel<<<NROWS / BLOCK, BLOCK, 0, stream>>>(Ym, Xm, Yt, Xt, out);
}